// Round 3
// baseline (1934.174 us; speedup 1.0000x reference)
//
#include <hip/hip_runtime.h>
#include <hip/hip_fp16.h>

// Fused MSE + SSIM loss, 32x3x512x512 fp32, MI355X — R7.
// R6 post-mortem: persistent strips collapsed VALUBusy 71%->25% (latency exposed,
// lockstep chunks, exact-fit grid). Lesson: throughput came from inter-block
// overlap, not intra-block balance (R4: TH=16, 8 blk/CU -> 105% busy).
// R7 = R5's packed-fp16 S/D math in R4's high-occupancy shape:
//   TH=16, LDS 13.4KB -> 8 blocks/CU (32 waves), grid 8x32x96 = 24576 blocks.
//   + R6's fused last-block finalize (one launch instead of two).
// Math (unchanged from R5): S=P+T, D=P-T; conv fields {S,D,S^2,D^2} as half2;
//   horizontal conv packed fp16 via staggered pairs (v_alignbit);
//   vertical conv packed fp16; SSIM from A,B,X,Y algebra; MSE = sum(D^2) free.

#define WSZ   512
#define TW    64
#define TH    16
#define HALO  5
#define IN_H  (TH + 2*HALO)    // 26 rows of horizontal-pass output
#define NPOS  32               // float4 slots per row
#define GX    (WSZ / TW)       // 8
#define GY    (WSZ / TH)       // 32
#define NSLOT 64
#define SSIM_C1 0.0001f
#define SSIM_C2 0.0009f

// 11-tap gaussian, sigma=1.5, normalized
#define W0 0.00102838f
#define W1 0.00759876f
#define W2 0.03600080f
#define W3 0.10936080f
#define W4 0.21300560f
#define W5 0.26601170f

static __device__ __forceinline__ __half2 pk(float a, float b) {
    return __builtin_bit_cast(__half2, __builtin_amdgcn_cvt_pkrtz(a, b));
}
// staggered pair: (lo.hi, hi.lo) == (x[2u+1], x[2u+2])
static __device__ __forceinline__ __half2 stagger(__half2 hi, __half2 lo) {
    return __builtin_bit_cast(__half2,
        __builtin_amdgcn_alignbit(__builtin_bit_cast(unsigned, hi),
                                  __builtin_bit_cast(unsigned, lo), 16));
}

__launch_bounds__(256, 8)
__global__ void fused_mse_ssim(const float* __restrict__ P,
                               const float* __restrict__ T,
                               float* __restrict__ ws,
                               float* __restrict__ out,
                               float invN, int nblocks) {
    __shared__ float4 sAB[IN_H][NPOS];   // fields per slot: S, D, SS, DD (half2)
    __shared__ float  red[2][4];
    __shared__ int    sLast;

    const int tid = threadIdx.x;
    const int gx0 = blockIdx.x * TW;
    const int gy0 = blockIdx.y * TH;
    const size_t plane = (size_t)blockIdx.z * (WSZ * (size_t)WSZ);
    const float* Pp = P + plane;
    const float* Tp = T + plane;
    const bool xedge = (blockIdx.x == 0) || (blockIdx.x == GX - 1);

    const float gwf[11] = {W0,W1,W2,W3,W4,W5,W4,W3,W2,W1,W0};
    unsigned gwh[11];   // half2(w,w) bit patterns, wave-uniform -> SGPR
    #pragma unroll
    for (int k = 0; k < 11; ++k)
        gwh[k] = __builtin_amdgcn_readfirstlane(
                     __builtin_bit_cast(unsigned, __float2half2_rn(gwf[k])));

    float mse = 0.f;

    // ---- stage A: packed-fp16 horizontal 11-tap on S,D,S^2,D^2; MSE folded in.
    // 208 items (26 rows x 8 px-groups) on 256 threads: single pass, no loop.
    if (tid < IN_H * 8) {
        const int r  = tid >> 3;
        const int q  = tid & 7;
        const int gy = gy0 - HALO + r;
        const int cb = gx0 + q * 8 - 8;            // leftmost loaded px (16B aligned)
        const float* prow = Pp + ((long)gy * WSZ + cb);
        const float* trow = Tp + ((long)gy * WSZ + cb);
        const bool rv   = ((unsigned)gy < (unsigned)WSZ);
        const bool mrow = ((unsigned)(r - HALO) < (unsigned)TH);

        const __half2 z = __float2half2_rn(0.f);
        __half2 As[12], Ad[12];

        if (!xedge) {
            if (rv) {
                #pragma unroll
                for (int b = 0; b < 6; ++b) {
                    const float4 pv = *(const float4*)(prow + 4 * b);
                    const float4 tv = *(const float4*)(trow + 4 * b);
                    const float s0 = pv.x + tv.x, s1 = pv.y + tv.y;
                    const float s2 = pv.z + tv.z, s3 = pv.w + tv.w;
                    const float d0 = pv.x - tv.x, d1 = pv.y - tv.y;
                    const float d2 = pv.z - tv.z, d3 = pv.w - tv.w;
                    As[2*b]   = pk(s0, s1); As[2*b+1] = pk(s2, s3);
                    Ad[2*b]   = pk(d0, d1); Ad[2*b+1] = pk(d2, d3);
                    if ((b == 2 || b == 3) && mrow) {
                        mse = fmaf(d0, d0, mse); mse = fmaf(d1, d1, mse);
                        mse = fmaf(d2, d2, mse); mse = fmaf(d3, d3, mse);
                    }
                }
            } else {
                #pragma unroll
                for (int b = 0; b < 12; ++b) { As[b] = z; Ad[b] = z; }
            }
        } else {
            #pragma unroll
            for (int b = 0; b < 6; ++b) {
                const unsigned cc = (unsigned)(cb + 4 * b);
                float4 pv = make_float4(0.f, 0.f, 0.f, 0.f);
                float4 tv = make_float4(0.f, 0.f, 0.f, 0.f);
                if (rv && cc < (unsigned)WSZ) {
                    pv = *(const float4*)(prow + 4 * b);
                    tv = *(const float4*)(trow + 4 * b);
                }
                const float s0 = pv.x + tv.x, s1 = pv.y + tv.y;
                const float s2 = pv.z + tv.z, s3 = pv.w + tv.w;
                const float d0 = pv.x - tv.x, d1 = pv.y - tv.y;
                const float d2 = pv.z - tv.z, d3 = pv.w - tv.w;
                As[2*b]   = pk(s0, s1); As[2*b+1] = pk(s2, s3);
                Ad[2*b]   = pk(d0, d1); Ad[2*b+1] = pk(d2, d3);
                if ((b == 2 || b == 3) && mrow) {
                    mse = fmaf(d0, d0, mse); mse = fmaf(d1, d1, mse);
                    mse = fmaf(d2, d2, mse); mse = fmaf(d3, d3, mse);
                }
            }
        }

        // packed conv: output pair m (=out px 2m,2m+1) needs px[3+2m+k], k=0..10
        __half2 aS[4]  = {z, z, z, z};
        __half2 aD[4]  = {z, z, z, z};
        __half2 aSS[4] = {z, z, z, z};
        __half2 aDD[4] = {z, z, z, z};

        #pragma unroll
        for (int jj = 0; jj <= 16; ++jj) {
            const int j = jj + 3;
            __half2 vs, vd;
            if (j & 1) {
                vs = stagger(As[(j >> 1) + 1], As[j >> 1]);
                vd = stagger(Ad[(j >> 1) + 1], Ad[j >> 1]);
            } else {
                vs = As[j >> 1];
                vd = Ad[j >> 1];
            }
            const __half2 vss = __hmul2(vs, vs);
            const __half2 vdd = __hmul2(vd, vd);
            #pragma unroll
            for (int m = 0; m < 4; ++m) {
                const int k = jj - 2 * m;
                if (k >= 0 && k < 11) {
                    const __half2 w = __builtin_bit_cast(__half2, gwh[k]);
                    aS[m]  = __hfma2(w, vs,  aS[m]);
                    aD[m]  = __hfma2(w, vd,  aD[m]);
                    aSS[m] = __hfma2(w, vss, aSS[m]);
                    aDD[m] = __hfma2(w, vdd, aDD[m]);
                }
            }
        }

        // slot-spread store: position pos=4q+m lives at col 8m+q
        #pragma unroll
        for (int m = 0; m < 4; ++m)
            sAB[r][8 * m + q] = make_float4(
                __builtin_bit_cast(float, aS[m]),  __builtin_bit_cast(float, aD[m]),
                __builtin_bit_cast(float, aSS[m]), __builtin_bit_cast(float, aDD[m]));
    }
    __syncthreads();

    // ---- stage B: vertical 11-tap (packed fp16), 2 output rows per thread ----
    const int q2  = tid & 31;
    const int col = ((q2 & 3) << 3) | (q2 >> 2);     // un-permute storage col
    const int y0  = (tid >> 5) << 1;                 // 0,2,...,14

    const __half2 z2 = __float2half2_rn(0.f);
    __half2 acc[2][4];
    #pragma unroll
    for (int a = 0; a < 2; ++a) {
        acc[a][0] = z2; acc[a][1] = z2; acc[a][2] = z2; acc[a][3] = z2;
    }

    #pragma unroll
    for (int j = 0; j < 12; ++j) {                   // window rows y0 .. y0+11
        const float4 ab = sAB[y0 + j][col];
        const __half2 hS  = __builtin_bit_cast(__half2, ab.x);
        const __half2 hD  = __builtin_bit_cast(__half2, ab.y);
        const __half2 hSS = __builtin_bit_cast(__half2, ab.z);
        const __half2 hDD = __builtin_bit_cast(__half2, ab.w);
        if (j < 11) {
            const __half2 w = __builtin_bit_cast(__half2, gwh[j]);
            acc[0][0] = __hfma2(w, hS,  acc[0][0]);
            acc[0][1] = __hfma2(w, hD,  acc[0][1]);
            acc[0][2] = __hfma2(w, hSS, acc[0][2]);
            acc[0][3] = __hfma2(w, hDD, acc[0][3]);
        }
        if (j >= 1) {
            const __half2 w = __builtin_bit_cast(__half2, gwh[j - 1]);
            acc[1][0] = __hfma2(w, hS,  acc[1][0]);
            acc[1][1] = __hfma2(w, hD,  acc[1][1]);
            acc[1][2] = __hfma2(w, hSS, acc[1][2]);
            acc[1][3] = __hfma2(w, hDD, acc[1][3]);
        }
    }

    // ---- SSIM epilogue (fp32), S/D algebra ----
    //   2mu12+C1 = 0.5(A^2-B^2)+C1 ; mu1^2+mu2^2+C1 = 0.5(A^2+B^2)+C1
    //   2s12+C2  = 0.5((X-Y)-(A^2-B^2))+C2 ; s1+s2+C2 = 0.5((X+Y)-(A^2+B^2))+C2
    float ssim = 0.f;
    #pragma unroll
    for (int a = 0; a < 2; ++a) {
        const float2 Av = __half22float2(acc[a][0]);
        const float2 Bv = __half22float2(acc[a][1]);
        const float2 Xv = __half22float2(acc[a][2]);
        const float2 Yv = __half22float2(acc[a][3]);
        #pragma unroll
        for (int e = 0; e < 2; ++e) {
            const float A = e ? Av.y : Av.x;
            const float B = e ? Bv.y : Bv.x;
            const float X = e ? Xv.y : Xv.x;
            const float Y = e ? Yv.y : Yv.x;
            const float a2 = A * A;
            const float b2 = B * B;
            const float P1 = a2 + b2;
            const float M1 = a2 - b2;
            const float num1 = fmaf(0.5f, M1, SSIM_C1);
            const float den1 = fmaf(0.5f, P1, SSIM_C1);
            const float num2 = fmaf(0.5f, (X - Y) - M1, SSIM_C2);
            const float den2 = fmaf(0.5f, (X + Y) - P1, SSIM_C2);
            ssim = fmaf(num1 * num2, __builtin_amdgcn_rcpf(den1 * den2), ssim);
        }
    }

    // ---- reduction: wave shuffle -> LDS -> 2 atomics -> last-block finalize ----
    #pragma unroll
    for (int off = 32; off > 0; off >>= 1) {
        mse  += __shfl_down(mse, off);
        ssim += __shfl_down(ssim, off);
    }
    const int wid = tid >> 6;
    if ((tid & 63) == 0) { red[0][wid] = mse; red[1][wid] = ssim; }
    __syncthreads();
    if (tid == 0) {
        const float m = red[0][0] + red[0][1] + red[0][2] + red[0][3];
        const float s = red[1][0] + red[1][1] + red[1][2] + red[1][3];
        const int bid  = (blockIdx.z * gridDim.y + blockIdx.y) * gridDim.x + blockIdx.x;
        const int slot = (bid & (NSLOT - 1)) * 16;     // 64B apart
        atomicAdd(&ws[slot + 0], m);
        atomicAdd(&ws[slot + 1], s);
        __threadfence();
        const unsigned old = __hip_atomic_fetch_add(
            (unsigned*)(ws + NSLOT * 16), 1u,
            __ATOMIC_ACQ_REL, __HIP_MEMORY_SCOPE_AGENT);
        sLast = (old == (unsigned)(nblocks - 1)) ? 1 : 0;
    }
    __syncthreads();
    if (sLast && tid < 64) {
        float m = __hip_atomic_load(&ws[tid * 16 + 0], __ATOMIC_ACQUIRE,
                                    __HIP_MEMORY_SCOPE_AGENT);
        float s = __hip_atomic_load(&ws[tid * 16 + 1], __ATOMIC_ACQUIRE,
                                    __HIP_MEMORY_SCOPE_AGENT);
        #pragma unroll
        for (int off = 32; off > 0; off >>= 1) {
            m += __shfl_down(m, off);
            s += __shfl_down(s, off);
        }
        if (tid == 0) out[0] = m * invN + 0.01f * (1.f - s * invN);
    }
}

extern "C" void kernel_launch(void* const* d_in, const int* in_sizes, int n_in,
                              void* d_out, int out_size, void* d_ws, size_t ws_size,
                              hipStream_t stream) {
    const float* P = (const float*)d_in[0];
    const float* T = (const float*)d_in[1];
    float* out = (float*)d_out;
    float* ws  = (float*)d_ws;

    const int planes  = in_sizes[0] / (WSZ * WSZ);     // 96
    const float invN  = 1.f / (float)in_sizes[0];
    const int nblocks = GX * GY * planes;              // 24576

    (void)hipMemsetAsync(ws, 0, (NSLOT * 16 + 16) * sizeof(float), stream);
    dim3 grid(GX, GY, planes);
    fused_mse_ssim<<<grid, 256, 0, stream>>>(P, T, ws, out, invN, nblocks);
}

// Round 4
// 249.112 us; speedup vs baseline: 7.7643x; 7.7643x over previous
//
#include <hip/hip_runtime.h>
#include <hip/hip_fp16.h>

// Fused MSE + SSIM loss, 32x3x512x512 fp32, MI355X — R8.
// R7 post-mortem: fused last-block finalize (per-block __threadfence + ACQ_REL
// fetch_add on ONE address, 24576 blocks) serialized at ~75ns each -> 1.8ms wall
// with all pipes idle. NEVER put device-scope fenced RMWs in a 24K-block grid.
// R8 = R7 with the ending reverted to R4's proven pattern: plain spread-slot
// atomicAdd (64 cachelines) + separate 64-thread finalize kernel (~2us launch).
// Everything else unchanged: R5 packed-fp16 S/D math, TH=16, 13.4KB LDS,
// 8 blocks/CU, grid 8x32x96 = 24576 blocks (R4 measured 105% VALUBusy here).

#define WSZ   512
#define TW    64
#define TH    16
#define HALO  5
#define IN_H  (TH + 2*HALO)    // 26 rows of horizontal-pass output
#define NPOS  32               // float4 slots per row
#define GX    (WSZ / TW)       // 8
#define GY    (WSZ / TH)       // 32
#define NSLOT 64
#define SSIM_C1 0.0001f
#define SSIM_C2 0.0009f

// 11-tap gaussian, sigma=1.5, normalized
#define W0 0.00102838f
#define W1 0.00759876f
#define W2 0.03600080f
#define W3 0.10936080f
#define W4 0.21300560f
#define W5 0.26601170f

static __device__ __forceinline__ __half2 pk(float a, float b) {
    return __builtin_bit_cast(__half2, __builtin_amdgcn_cvt_pkrtz(a, b));
}
// staggered pair: (lo.hi, hi.lo) == (x[2u+1], x[2u+2])
static __device__ __forceinline__ __half2 stagger(__half2 hi, __half2 lo) {
    return __builtin_bit_cast(__half2,
        __builtin_amdgcn_alignbit(__builtin_bit_cast(unsigned, hi),
                                  __builtin_bit_cast(unsigned, lo), 16));
}

__launch_bounds__(256, 8)
__global__ void fused_mse_ssim(const float* __restrict__ P,
                               const float* __restrict__ T,
                               float* __restrict__ ws) {
    __shared__ float4 sAB[IN_H][NPOS];   // fields per slot: S, D, SS, DD (half2)
    __shared__ float  red[2][4];

    const int tid = threadIdx.x;
    const int gx0 = blockIdx.x * TW;
    const int gy0 = blockIdx.y * TH;
    const size_t plane = (size_t)blockIdx.z * (WSZ * (size_t)WSZ);
    const float* Pp = P + plane;
    const float* Tp = T + plane;
    const bool xedge = (blockIdx.x == 0) || (blockIdx.x == GX - 1);

    const float gwf[11] = {W0,W1,W2,W3,W4,W5,W4,W3,W2,W1,W0};
    unsigned gwh[11];   // half2(w,w) bit patterns, wave-uniform -> SGPR
    #pragma unroll
    for (int k = 0; k < 11; ++k)
        gwh[k] = __builtin_amdgcn_readfirstlane(
                     __builtin_bit_cast(unsigned, __float2half2_rn(gwf[k])));

    float mse = 0.f;

    // ---- stage A: packed-fp16 horizontal 11-tap on S,D,S^2,D^2; MSE folded in.
    // 208 items (26 rows x 8 px-groups) on 256 threads: single pass, no loop.
    if (tid < IN_H * 8) {
        const int r  = tid >> 3;
        const int q  = tid & 7;
        const int gy = gy0 - HALO + r;
        const int cb = gx0 + q * 8 - 8;            // leftmost loaded px (16B aligned)
        const float* prow = Pp + ((long)gy * WSZ + cb);
        const float* trow = Tp + ((long)gy * WSZ + cb);
        const bool rv   = ((unsigned)gy < (unsigned)WSZ);
        const bool mrow = ((unsigned)(r - HALO) < (unsigned)TH);

        const __half2 z = __float2half2_rn(0.f);
        __half2 As[12], Ad[12];

        if (!xedge) {
            if (rv) {
                #pragma unroll
                for (int b = 0; b < 6; ++b) {
                    const float4 pv = *(const float4*)(prow + 4 * b);
                    const float4 tv = *(const float4*)(trow + 4 * b);
                    const float s0 = pv.x + tv.x, s1 = pv.y + tv.y;
                    const float s2 = pv.z + tv.z, s3 = pv.w + tv.w;
                    const float d0 = pv.x - tv.x, d1 = pv.y - tv.y;
                    const float d2 = pv.z - tv.z, d3 = pv.w - tv.w;
                    As[2*b]   = pk(s0, s1); As[2*b+1] = pk(s2, s3);
                    Ad[2*b]   = pk(d0, d1); Ad[2*b+1] = pk(d2, d3);
                    if ((b == 2 || b == 3) && mrow) {
                        mse = fmaf(d0, d0, mse); mse = fmaf(d1, d1, mse);
                        mse = fmaf(d2, d2, mse); mse = fmaf(d3, d3, mse);
                    }
                }
            } else {
                #pragma unroll
                for (int b = 0; b < 12; ++b) { As[b] = z; Ad[b] = z; }
            }
        } else {
            #pragma unroll
            for (int b = 0; b < 6; ++b) {
                const unsigned cc = (unsigned)(cb + 4 * b);
                float4 pv = make_float4(0.f, 0.f, 0.f, 0.f);
                float4 tv = make_float4(0.f, 0.f, 0.f, 0.f);
                if (rv && cc < (unsigned)WSZ) {
                    pv = *(const float4*)(prow + 4 * b);
                    tv = *(const float4*)(trow + 4 * b);
                }
                const float s0 = pv.x + tv.x, s1 = pv.y + tv.y;
                const float s2 = pv.z + tv.z, s3 = pv.w + tv.w;
                const float d0 = pv.x - tv.x, d1 = pv.y - tv.y;
                const float d2 = pv.z - tv.z, d3 = pv.w - tv.w;
                As[2*b]   = pk(s0, s1); As[2*b+1] = pk(s2, s3);
                Ad[2*b]   = pk(d0, d1); Ad[2*b+1] = pk(d2, d3);
                if ((b == 2 || b == 3) && mrow) {
                    mse = fmaf(d0, d0, mse); mse = fmaf(d1, d1, mse);
                    mse = fmaf(d2, d2, mse); mse = fmaf(d3, d3, mse);
                }
            }
        }

        // packed conv: output pair m (=out px 2m,2m+1) needs px[3+2m+k], k=0..10
        __half2 aS[4]  = {z, z, z, z};
        __half2 aD[4]  = {z, z, z, z};
        __half2 aSS[4] = {z, z, z, z};
        __half2 aDD[4] = {z, z, z, z};

        #pragma unroll
        for (int jj = 0; jj <= 16; ++jj) {
            const int j = jj + 3;
            __half2 vs, vd;
            if (j & 1) {
                vs = stagger(As[(j >> 1) + 1], As[j >> 1]);
                vd = stagger(Ad[(j >> 1) + 1], Ad[j >> 1]);
            } else {
                vs = As[j >> 1];
                vd = Ad[j >> 1];
            }
            const __half2 vss = __hmul2(vs, vs);
            const __half2 vdd = __hmul2(vd, vd);
            #pragma unroll
            for (int m = 0; m < 4; ++m) {
                const int k = jj - 2 * m;
                if (k >= 0 && k < 11) {
                    const __half2 w = __builtin_bit_cast(__half2, gwh[k]);
                    aS[m]  = __hfma2(w, vs,  aS[m]);
                    aD[m]  = __hfma2(w, vd,  aD[m]);
                    aSS[m] = __hfma2(w, vss, aSS[m]);
                    aDD[m] = __hfma2(w, vdd, aDD[m]);
                }
            }
        }

        // slot-spread store: position pos=4q+m lives at col 8m+q
        #pragma unroll
        for (int m = 0; m < 4; ++m)
            sAB[r][8 * m + q] = make_float4(
                __builtin_bit_cast(float, aS[m]),  __builtin_bit_cast(float, aD[m]),
                __builtin_bit_cast(float, aSS[m]), __builtin_bit_cast(float, aDD[m]));
    }
    __syncthreads();

    // ---- stage B: vertical 11-tap (packed fp16), 2 output rows per thread ----
    const int q2  = tid & 31;
    const int col = ((q2 & 3) << 3) | (q2 >> 2);     // un-permute storage col
    const int y0  = (tid >> 5) << 1;                 // 0,2,...,14

    const __half2 z2 = __float2half2_rn(0.f);
    __half2 acc[2][4];
    #pragma unroll
    for (int a = 0; a < 2; ++a) {
        acc[a][0] = z2; acc[a][1] = z2; acc[a][2] = z2; acc[a][3] = z2;
    }

    #pragma unroll
    for (int j = 0; j < 12; ++j) {                   // window rows y0 .. y0+11
        const float4 ab = sAB[y0 + j][col];
        const __half2 hS  = __builtin_bit_cast(__half2, ab.x);
        const __half2 hD  = __builtin_bit_cast(__half2, ab.y);
        const __half2 hSS = __builtin_bit_cast(__half2, ab.z);
        const __half2 hDD = __builtin_bit_cast(__half2, ab.w);
        if (j < 11) {
            const __half2 w = __builtin_bit_cast(__half2, gwh[j]);
            acc[0][0] = __hfma2(w, hS,  acc[0][0]);
            acc[0][1] = __hfma2(w, hD,  acc[0][1]);
            acc[0][2] = __hfma2(w, hSS, acc[0][2]);
            acc[0][3] = __hfma2(w, hDD, acc[0][3]);
        }
        if (j >= 1) {
            const __half2 w = __builtin_bit_cast(__half2, gwh[j - 1]);
            acc[1][0] = __hfma2(w, hS,  acc[1][0]);
            acc[1][1] = __hfma2(w, hD,  acc[1][1]);
            acc[1][2] = __hfma2(w, hSS, acc[1][2]);
            acc[1][3] = __hfma2(w, hDD, acc[1][3]);
        }
    }

    // ---- SSIM epilogue (fp32), S/D algebra ----
    //   2mu12+C1 = 0.5(A^2-B^2)+C1 ; mu1^2+mu2^2+C1 = 0.5(A^2+B^2)+C1
    //   2s12+C2  = 0.5((X-Y)-(A^2-B^2))+C2 ; s1+s2+C2 = 0.5((X+Y)-(A^2+B^2))+C2
    float ssim = 0.f;
    #pragma unroll
    for (int a = 0; a < 2; ++a) {
        const float2 Av = __half22float2(acc[a][0]);
        const float2 Bv = __half22float2(acc[a][1]);
        const float2 Xv = __half22float2(acc[a][2]);
        const float2 Yv = __half22float2(acc[a][3]);
        #pragma unroll
        for (int e = 0; e < 2; ++e) {
            const float A = e ? Av.y : Av.x;
            const float B = e ? Bv.y : Bv.x;
            const float X = e ? Xv.y : Xv.x;
            const float Y = e ? Yv.y : Yv.x;
            const float a2 = A * A;
            const float b2 = B * B;
            const float P1 = a2 + b2;
            const float M1 = a2 - b2;
            const float num1 = fmaf(0.5f, M1, SSIM_C1);
            const float den1 = fmaf(0.5f, P1, SSIM_C1);
            const float num2 = fmaf(0.5f, (X - Y) - M1, SSIM_C2);
            const float den2 = fmaf(0.5f, (X + Y) - P1, SSIM_C2);
            ssim = fmaf(num1 * num2, __builtin_amdgcn_rcpf(den1 * den2), ssim);
        }
    }

    // ---- reduction: wave shuffle -> LDS -> 2 plain atomics into a spread slot ----
    #pragma unroll
    for (int off = 32; off > 0; off >>= 1) {
        mse  += __shfl_down(mse, off);
        ssim += __shfl_down(ssim, off);
    }
    const int wid = tid >> 6;
    if ((tid & 63) == 0) { red[0][wid] = mse; red[1][wid] = ssim; }
    __syncthreads();
    if (tid == 0) {
        const float m = red[0][0] + red[0][1] + red[0][2] + red[0][3];
        const float s = red[1][0] + red[1][1] + red[1][2] + red[1][3];
        const int bid  = (blockIdx.z * gridDim.y + blockIdx.y) * gridDim.x + blockIdx.x;
        const int slot = (bid & (NSLOT - 1)) * 16;     // 64B apart -> no line bouncing
        atomicAdd(&ws[slot + 0], m);
        atomicAdd(&ws[slot + 1], s);
    }
}

__global__ void finalize_loss(const float* __restrict__ ws,
                              float* __restrict__ out, float invN) {
    const int t = threadIdx.x;           // 64 threads
    float m = ws[t * 16 + 0];
    float s = ws[t * 16 + 1];
    #pragma unroll
    for (int off = 32; off > 0; off >>= 1) {
        m += __shfl_down(m, off);
        s += __shfl_down(s, off);
    }
    if (t == 0) out[0] = m * invN + 0.01f * (1.f - s * invN);
}

extern "C" void kernel_launch(void* const* d_in, const int* in_sizes, int n_in,
                              void* d_out, int out_size, void* d_ws, size_t ws_size,
                              hipStream_t stream) {
    const float* P = (const float*)d_in[0];
    const float* T = (const float*)d_in[1];
    float* out = (float*)d_out;
    float* ws  = (float*)d_ws;

    const int planes = in_sizes[0] / (WSZ * WSZ);     // 96
    const float invN = 1.f / (float)in_sizes[0];

    (void)hipMemsetAsync(ws, 0, NSLOT * 16 * sizeof(float), stream);
    dim3 grid(GX, GY, planes);
    fused_mse_ssim<<<grid, 256, 0, stream>>>(P, T, ws);
    finalize_loss<<<1, 64, 0, stream>>>(ws, out, invN);
}

// Round 5
// 237.698 us; speedup vs baseline: 8.1371x; 1.0480x over previous
//
#include <hip/hip_runtime.h>
#include <hip/hip_fp16.h>

// Fused MSE + SSIM loss, 32x3x512x512 fp32, MI355X — R9.
// Best-so-far: R5 (TH=32, 95.7us, VALUBusy 71%). R8 (TH=16) = 110us: halo work
// beat occupancy. R9 attacks R5's two enumerated idle sources while keeping its
// proven math:
//  (1) TH=64, 640-thread blocks: 592 stage-A items -> EXACTLY one per thread
//      (R5: waves 0-1 issued 2 items; block wall was 2A+1B).
//  (2) Vertical halo 74/64 = 1.156x (R5: 42/32 = 1.31x) -> -12% stage-A work.
//  (3) 30 waves/CU (3 blocks x 10 waves, LDS 37.9KB), 6144 blocks for overlap.
//  (4) Rotation swizzle for LDS cols: store (pos+r)&31, read (q2+lr)&31 —
//      bank-conflict-free writes AND reads (verified by bank arithmetic).
// Math identical to R5/R8: S=P+T, D=P-T; packed-fp16 conv {S,D,S^2,D^2};
// SSIM via A,B,X,Y algebra; MSE = sum(D^2) folded into stage A.
// Ending: plain spread-slot atomics + separate finalize kernel (R7 lesson:
// NEVER per-block device-scope fenced RMW at 10K-block scale).

#define WSZ   512
#define TW    64
#define TH    64
#define HALO  5
#define IN_H  (TH + 2*HALO)    // 74 rows of horizontal-pass output
#define GX    (WSZ / TW)       // 8
#define GY    (WSZ / TH)       // 8
#define NTHR  640
#define NSLOT 64
#define SSIM_C1 0.0001f
#define SSIM_C2 0.0009f

// 11-tap gaussian, sigma=1.5, normalized
#define W0 0.00102838f
#define W1 0.00759876f
#define W2 0.03600080f
#define W3 0.10936080f
#define W4 0.21300560f
#define W5 0.26601170f

static __device__ __forceinline__ __half2 pk(float a, float b) {
    return __builtin_bit_cast(__half2, __builtin_amdgcn_cvt_pkrtz(a, b));
}
// staggered pair: (lo.hi, hi.lo) == (x[2u+1], x[2u+2])
static __device__ __forceinline__ __half2 stagger(__half2 hi, __half2 lo) {
    return __builtin_bit_cast(__half2,
        __builtin_amdgcn_alignbit(__builtin_bit_cast(unsigned, hi),
                                  __builtin_bit_cast(unsigned, lo), 16));
}

__launch_bounds__(NTHR, 8)
__global__ void fused_mse_ssim(const float* __restrict__ P,
                               const float* __restrict__ T,
                               float* __restrict__ ws) {
    __shared__ float4 sAB[IN_H][32];    // fields per slot: S, D, SS, DD (half2)
    __shared__ float  red[2][NTHR / 64];

    const int tid = threadIdx.x;
    const int gx0 = blockIdx.x * TW;
    const int gy0 = blockIdx.y * TH;
    const size_t plane = (size_t)blockIdx.z * (WSZ * (size_t)WSZ);
    const float* Pp = P + plane;
    const float* Tp = T + plane;
    const bool xedge = (blockIdx.x == 0) || (blockIdx.x == GX - 1);

    const float gwf[11] = {W0,W1,W2,W3,W4,W5,W4,W3,W2,W1,W0};
    unsigned gwh[11];   // half2(w,w) bit patterns, wave-uniform -> SGPR
    #pragma unroll
    for (int k = 0; k < 11; ++k)
        gwh[k] = __builtin_amdgcn_readfirstlane(
                     __builtin_bit_cast(unsigned, __float2half2_rn(gwf[k])));

    float mse = 0.f;

    // ---- stage A: packed-fp16 horizontal 11-tap on S,D,S^2,D^2; MSE folded in.
    // 592 items (74 rows x 8 px-groups) on 640 threads: one item per thread.
    if (tid < IN_H * 8) {
        const int r  = tid >> 3;
        const int g  = tid & 7;
        const int gy = gy0 - HALO + r;
        const int cb = gx0 + g * 8 - 8;            // leftmost loaded px (16B aligned)
        const float* prow = Pp + ((long)gy * WSZ + cb);
        const float* trow = Tp + ((long)gy * WSZ + cb);
        const bool rv   = ((unsigned)gy < (unsigned)WSZ);
        const bool mrow = ((unsigned)(r - HALO) < (unsigned)TH);

        const __half2 z = __float2half2_rn(0.f);
        __half2 As[12], Ad[12];

        if (!xedge) {
            if (rv) {
                #pragma unroll
                for (int b = 0; b < 6; ++b) {
                    const float4 pv = *(const float4*)(prow + 4 * b);
                    const float4 tv = *(const float4*)(trow + 4 * b);
                    const float s0 = pv.x + tv.x, s1 = pv.y + tv.y;
                    const float s2 = pv.z + tv.z, s3 = pv.w + tv.w;
                    const float d0 = pv.x - tv.x, d1 = pv.y - tv.y;
                    const float d2 = pv.z - tv.z, d3 = pv.w - tv.w;
                    As[2*b]   = pk(s0, s1); As[2*b+1] = pk(s2, s3);
                    Ad[2*b]   = pk(d0, d1); Ad[2*b+1] = pk(d2, d3);
                    if ((b == 2 || b == 3) && mrow) {
                        mse = fmaf(d0, d0, mse); mse = fmaf(d1, d1, mse);
                        mse = fmaf(d2, d2, mse); mse = fmaf(d3, d3, mse);
                    }
                }
            } else {
                #pragma unroll
                for (int b = 0; b < 12; ++b) { As[b] = z; Ad[b] = z; }
            }
        } else {
            #pragma unroll
            for (int b = 0; b < 6; ++b) {
                const unsigned cc = (unsigned)(cb + 4 * b);
                float4 pv = make_float4(0.f, 0.f, 0.f, 0.f);
                float4 tv = make_float4(0.f, 0.f, 0.f, 0.f);
                if (rv && cc < (unsigned)WSZ) {
                    pv = *(const float4*)(prow + 4 * b);
                    tv = *(const float4*)(trow + 4 * b);
                }
                const float s0 = pv.x + tv.x, s1 = pv.y + tv.y;
                const float s2 = pv.z + tv.z, s3 = pv.w + tv.w;
                const float d0 = pv.x - tv.x, d1 = pv.y - tv.y;
                const float d2 = pv.z - tv.z, d3 = pv.w - tv.w;
                As[2*b]   = pk(s0, s1); As[2*b+1] = pk(s2, s3);
                Ad[2*b]   = pk(d0, d1); Ad[2*b+1] = pk(d2, d3);
                if ((b == 2 || b == 3) && mrow) {
                    mse = fmaf(d0, d0, mse); mse = fmaf(d1, d1, mse);
                    mse = fmaf(d2, d2, mse); mse = fmaf(d3, d3, mse);
                }
            }
        }

        // packed conv: output pair m (=out px 2m,2m+1) needs px[3+2m+k], k=0..10
        __half2 aS[4]  = {z, z, z, z};
        __half2 aD[4]  = {z, z, z, z};
        __half2 aSS[4] = {z, z, z, z};
        __half2 aDD[4] = {z, z, z, z};

        #pragma unroll
        for (int jj = 0; jj <= 16; ++jj) {
            const int j = jj + 3;
            __half2 vs, vd;
            if (j & 1) {
                vs = stagger(As[(j >> 1) + 1], As[j >> 1]);
                vd = stagger(Ad[(j >> 1) + 1], Ad[j >> 1]);
            } else {
                vs = As[j >> 1];
                vd = Ad[j >> 1];
            }
            const __half2 vss = __hmul2(vs, vs);
            const __half2 vdd = __hmul2(vd, vd);
            #pragma unroll
            for (int m = 0; m < 4; ++m) {
                const int k = jj - 2 * m;
                if (k >= 0 && k < 11) {
                    const __half2 w = __builtin_bit_cast(__half2, gwh[k]);
                    aS[m]  = __hfma2(w, vs,  aS[m]);
                    aD[m]  = __hfma2(w, vd,  aD[m]);
                    aSS[m] = __hfma2(w, vss, aSS[m]);
                    aDD[m] = __hfma2(w, vdd, aDD[m]);
                }
            }
        }

        // rotation-swizzled store: pair pos = 4g+m of row r lives at col (pos+r)&31
        #pragma unroll
        for (int m = 0; m < 4; ++m)
            sAB[r][(4 * g + m + r) & 31] = make_float4(
                __builtin_bit_cast(float, aS[m]),  __builtin_bit_cast(float, aD[m]),
                __builtin_bit_cast(float, aSS[m]), __builtin_bit_cast(float, aDD[m]));
    }
    __syncthreads();

    float ssim = 0.f;

    // ---- stage B: vertical 11-tap (packed fp16), 4 output rows per thread ----
    // 512 threads (waves 0-7); waves 8-9 skip to the reduction.
    if (tid < 512) {
        const int q2 = tid & 31;                     // true half2 column
        const int y0 = (tid >> 5) << 2;              // 0,4,...,60

        const __half2 z2 = __float2half2_rn(0.f);
        __half2 acc[4][4];
        #pragma unroll
        for (int a = 0; a < 4; ++a) {
            acc[a][0] = z2; acc[a][1] = z2; acc[a][2] = z2; acc[a][3] = z2;
        }

        #pragma unroll
        for (int j = 0; j < 14; ++j) {               // window rows y0 .. y0+13
            const int lr = y0 + j;
            const float4 ab = sAB[lr][(q2 + lr) & 31];   // un-rotate
            const __half2 hS  = __builtin_bit_cast(__half2, ab.x);
            const __half2 hD  = __builtin_bit_cast(__half2, ab.y);
            const __half2 hSS = __builtin_bit_cast(__half2, ab.z);
            const __half2 hDD = __builtin_bit_cast(__half2, ab.w);
            #pragma unroll
            for (int a = 0; a < 4; ++a) {
                const int k = j - a;
                if (k >= 0 && k < 11) {
                    const __half2 w = __builtin_bit_cast(__half2, gwh[k]);
                    acc[a][0] = __hfma2(w, hS,  acc[a][0]);
                    acc[a][1] = __hfma2(w, hD,  acc[a][1]);
                    acc[a][2] = __hfma2(w, hSS, acc[a][2]);
                    acc[a][3] = __hfma2(w, hDD, acc[a][3]);
                }
            }
        }

        // SSIM epilogue (fp32), S/D algebra:
        //   2mu12+C1 = 0.5(A^2-B^2)+C1 ; mu1^2+mu2^2+C1 = 0.5(A^2+B^2)+C1
        //   2s12+C2  = 0.5((X-Y)-(A^2-B^2))+C2 ; s1+s2+C2 = 0.5((X+Y)-(A^2+B^2))+C2
        #pragma unroll
        for (int a = 0; a < 4; ++a) {
            const float2 Av = __half22float2(acc[a][0]);
            const float2 Bv = __half22float2(acc[a][1]);
            const float2 Xv = __half22float2(acc[a][2]);
            const float2 Yv = __half22float2(acc[a][3]);
            #pragma unroll
            for (int e = 0; e < 2; ++e) {
                const float A = e ? Av.y : Av.x;
                const float B = e ? Bv.y : Bv.x;
                const float X = e ? Xv.y : Xv.x;
                const float Y = e ? Yv.y : Yv.x;
                const float a2 = A * A;
                const float b2 = B * B;
                const float P1 = a2 + b2;
                const float M1 = a2 - b2;
                const float num1 = fmaf(0.5f, M1, SSIM_C1);
                const float den1 = fmaf(0.5f, P1, SSIM_C1);
                const float num2 = fmaf(0.5f, (X - Y) - M1, SSIM_C2);
                const float den2 = fmaf(0.5f, (X + Y) - P1, SSIM_C2);
                ssim = fmaf(num1 * num2, __builtin_amdgcn_rcpf(den1 * den2), ssim);
            }
        }
    }

    // ---- reduction: wave shuffle -> LDS -> 2 plain atomics into a spread slot ----
    #pragma unroll
    for (int off = 32; off > 0; off >>= 1) {
        mse  += __shfl_down(mse, off);
        ssim += __shfl_down(ssim, off);
    }
    const int wid = tid >> 6;
    if ((tid & 63) == 0) { red[0][wid] = mse; red[1][wid] = ssim; }
    __syncthreads();
    if (tid == 0) {
        float m = 0.f, s = 0.f;
        #pragma unroll
        for (int w = 0; w < NTHR / 64; ++w) { m += red[0][w]; s += red[1][w]; }
        const int bid  = (blockIdx.z * gridDim.y + blockIdx.y) * gridDim.x + blockIdx.x;
        const int slot = (bid & (NSLOT - 1)) * 16;     // 64B apart -> no line bouncing
        atomicAdd(&ws[slot + 0], m);
        atomicAdd(&ws[slot + 1], s);
    }
}

__global__ void finalize_loss(const float* __restrict__ ws,
                              float* __restrict__ out, float invN) {
    const int t = threadIdx.x;           // 64 threads
    float m = ws[t * 16 + 0];
    float s = ws[t * 16 + 1];
    #pragma unroll
    for (int off = 32; off > 0; off >>= 1) {
        m += __shfl_down(m, off);
        s += __shfl_down(s, off);
    }
    if (t == 0) out[0] = m * invN + 0.01f * (1.f - s * invN);
}

extern "C" void kernel_launch(void* const* d_in, const int* in_sizes, int n_in,
                              void* d_out, int out_size, void* d_ws, size_t ws_size,
                              hipStream_t stream) {
    const float* P = (const float*)d_in[0];
    const float* T = (const float*)d_in[1];
    float* out = (float*)d_out;
    float* ws  = (float*)d_ws;

    const int planes = in_sizes[0] / (WSZ * WSZ);     // 96
    const float invN = 1.f / (float)in_sizes[0];

    (void)hipMemsetAsync(ws, 0, NSLOT * 16 * sizeof(float), stream);
    dim3 grid(GX, GY, planes);
    fused_mse_ssim<<<grid, NTHR, 0, stream>>>(P, T, ws);
    finalize_loss<<<1, 64, 0, stream>>>(ws, out, invN);
}

// Round 7
// 231.547 us; speedup vs baseline: 8.3533x; 1.0266x over previous
//
#include <hip/hip_runtime.h>
#include <hip/hip_fp16.h>

// Fused MSE + SSIM loss, 32x3x512x512 fp32, MI355X — R11 (R10 + compile fix).
// History: R5 (TH=32) = 95.7us best; R6/R8/R9 structure variants all regressed;
// busy-time pinned ~68us, MfmaUtil 0 every round. R10/R11 cut the busy floor by
// moving the VERTICAL conv to the idle matrix pipe:
//   out[32][64] = W[32x42] x h[42][64], W = banded gaussian Toeplitz.
//   Per 16-row M-tile: 2 K-tiles of v_mfma_f32_16x16x16_f16.
//   A-operand = weights (2 frags, built per-lane once: gw[16c+4t+i-ly]).
//   B-operand = h-conv data from LDS float4 rows: 4x ds_read_b128 per K-window
//     + v_perm_b32 to split the 4 packed fields (even/odd px -> lo/hi half).
//   16 MFMA/wave replace 176 pk_fma; vertical accum becomes fp32 (C-regs).
// R11 fix: __builtin_amdgcn_cvt_pkrtz returns __fp16x2; bit_cast to unsigned
// (the pk() helper already did this; the A-frag builder didn't).
// Stage A unchanged from R5 except rotation store col (pos+r)&31 (R9-proven)
// and rows 42..47 zero-filled (MFMA K-tiles read up to row 47).
// Ending: spread-slot atomics + separate finalize (R7 lesson: no per-block
// device-scope fenced RMW).

#define WSZ   512
#define TW    64
#define TH    32
#define HALO  5
#define IN_H  (TH + 2*HALO)    // 42 rows of horizontal-pass output
#define BUFR  48               // padded to 48 for MFMA K-tile reads
#define GX    (WSZ / TW)       // 8
#define GY    (WSZ / TH)       // 16
#define NSLOT 64
#define SSIM_C1 0.0001f
#define SSIM_C2 0.0009f

// 11-tap gaussian, sigma=1.5, normalized
#define W0 0.00102838f
#define W1 0.00759876f
#define W2 0.03600080f
#define W3 0.10936080f
#define W4 0.21300560f
#define W5 0.26601170f

typedef _Float16 f16x4 __attribute__((ext_vector_type(4)));
typedef float    f32x4 __attribute__((ext_vector_type(4)));

static __device__ __forceinline__ __half2 pk(float a, float b) {
    return __builtin_bit_cast(__half2, __builtin_amdgcn_cvt_pkrtz(a, b));
}
static __device__ __forceinline__ unsigned pku(float a, float b) {
    return __builtin_bit_cast(unsigned, __builtin_amdgcn_cvt_pkrtz(a, b));
}
// staggered pair: (lo.hi, hi.lo) == (x[2u+1], x[2u+2])
static __device__ __forceinline__ __half2 stagger(__half2 hi, __half2 lo) {
    return __builtin_bit_cast(__half2,
        __builtin_amdgcn_alignbit(__builtin_bit_cast(unsigned, hi),
                                  __builtin_bit_cast(unsigned, lo), 16));
}

__launch_bounds__(256, 6)
__global__ void fused_mse_ssim(const float* __restrict__ P,
                               const float* __restrict__ T,
                               float* __restrict__ ws) {
    __shared__ float4 sAB[BUFR][32];    // fields per slot: S, D, SS, DD (half2)
    __shared__ float  red[2][4];

    const int tid = threadIdx.x;
    const int gx0 = blockIdx.x * TW;
    const int gy0 = blockIdx.y * TH;
    const size_t plane = (size_t)blockIdx.z * (WSZ * (size_t)WSZ);
    const float* Pp = P + plane;
    const float* Tp = T + plane;
    const bool xedge = (blockIdx.x == 0) || (blockIdx.x == GX - 1);

    const float gwf[11] = {W0,W1,W2,W3,W4,W5,W4,W3,W2,W1,W0};
    unsigned gwh[11];   // half2(w,w) bit patterns, wave-uniform -> SGPR
    #pragma unroll
    for (int k = 0; k < 11; ++k)
        gwh[k] = __builtin_amdgcn_readfirstlane(
                     __builtin_bit_cast(unsigned, __float2half2_rn(gwf[k])));

    float mse = 0.f;

    // zero-fill pad rows 42..47 (read by MFMA K-tiles; weights there are 0,
    // but uninitialized LDS could hold Inf/NaN patterns)
    if (tid < 192)
        sAB[IN_H + (tid >> 5)][tid & 31] = make_float4(0.f, 0.f, 0.f, 0.f);

    // ---- stage A (R5-proven): packed-fp16 horizontal 11-tap on S,D,S^2,D^2 ----
    for (int it = tid; it < IN_H * 8; it += 256) {
        const int r  = it >> 3;
        const int q  = it & 7;
        const int gy = gy0 - HALO + r;
        const int cb = gx0 + q * 8 - 8;            // leftmost loaded px (16B aligned)
        const float* prow = Pp + ((long)gy * WSZ + cb);
        const float* trow = Tp + ((long)gy * WSZ + cb);
        const bool rv   = ((unsigned)gy < (unsigned)WSZ);
        const bool mrow = ((unsigned)(r - HALO) < (unsigned)TH);

        const __half2 z = __float2half2_rn(0.f);
        __half2 As[12], Ad[12];

        if (!xedge) {
            if (rv) {
                #pragma unroll
                for (int b = 0; b < 6; ++b) {
                    const float4 pv = *(const float4*)(prow + 4 * b);
                    const float4 tv = *(const float4*)(trow + 4 * b);
                    const float s0 = pv.x + tv.x, s1 = pv.y + tv.y;
                    const float s2 = pv.z + tv.z, s3 = pv.w + tv.w;
                    const float d0 = pv.x - tv.x, d1 = pv.y - tv.y;
                    const float d2 = pv.z - tv.z, d3 = pv.w - tv.w;
                    As[2*b]   = pk(s0, s1); As[2*b+1] = pk(s2, s3);
                    Ad[2*b]   = pk(d0, d1); Ad[2*b+1] = pk(d2, d3);
                    if ((b == 2 || b == 3) && mrow) {
                        mse = fmaf(d0, d0, mse); mse = fmaf(d1, d1, mse);
                        mse = fmaf(d2, d2, mse); mse = fmaf(d3, d3, mse);
                    }
                }
            } else {
                #pragma unroll
                for (int b = 0; b < 12; ++b) { As[b] = z; Ad[b] = z; }
            }
        } else {
            #pragma unroll
            for (int b = 0; b < 6; ++b) {
                const unsigned cc = (unsigned)(cb + 4 * b);
                float4 pv = make_float4(0.f, 0.f, 0.f, 0.f);
                float4 tv = make_float4(0.f, 0.f, 0.f, 0.f);
                if (rv && cc < (unsigned)WSZ) {
                    pv = *(const float4*)(prow + 4 * b);
                    tv = *(const float4*)(trow + 4 * b);
                }
                const float s0 = pv.x + tv.x, s1 = pv.y + tv.y;
                const float s2 = pv.z + tv.z, s3 = pv.w + tv.w;
                const float d0 = pv.x - tv.x, d1 = pv.y - tv.y;
                const float d2 = pv.z - tv.z, d3 = pv.w - tv.w;
                As[2*b]   = pk(s0, s1); As[2*b+1] = pk(s2, s3);
                Ad[2*b]   = pk(d0, d1); Ad[2*b+1] = pk(d2, d3);
                if ((b == 2 || b == 3) && mrow) {
                    mse = fmaf(d0, d0, mse); mse = fmaf(d1, d1, mse);
                    mse = fmaf(d2, d2, mse); mse = fmaf(d3, d3, mse);
                }
            }
        }

        // packed conv: output pair m (=out px 2m,2m+1) needs px[3+2m+k], k=0..10
        __half2 aS[4]  = {z, z, z, z};
        __half2 aD[4]  = {z, z, z, z};
        __half2 aSS[4] = {z, z, z, z};
        __half2 aDD[4] = {z, z, z, z};

        #pragma unroll
        for (int jj = 0; jj <= 16; ++jj) {
            const int j = jj + 3;
            __half2 vs, vd;
            if (j & 1) {
                vs = stagger(As[(j >> 1) + 1], As[j >> 1]);
                vd = stagger(Ad[(j >> 1) + 1], Ad[j >> 1]);
            } else {
                vs = As[j >> 1];
                vd = Ad[j >> 1];
            }
            const __half2 vss = __hmul2(vs, vs);
            const __half2 vdd = __hmul2(vd, vd);
            #pragma unroll
            for (int m = 0; m < 4; ++m) {
                const int k = jj - 2 * m;
                if (k >= 0 && k < 11) {
                    const __half2 w = __builtin_bit_cast(__half2, gwh[k]);
                    aS[m]  = __hfma2(w, vs,  aS[m]);
                    aD[m]  = __hfma2(w, vd,  aD[m]);
                    aSS[m] = __hfma2(w, vss, aSS[m]);
                    aDD[m] = __hfma2(w, vdd, aDD[m]);
                }
            }
        }

        // rotation-swizzled store (R9-proven): pair pos=4q+m of row r at col (pos+r)&31
        #pragma unroll
        for (int m = 0; m < 4; ++m)
            sAB[r][(4 * q + m + r) & 31] = make_float4(
                __builtin_bit_cast(float, aS[m]),  __builtin_bit_cast(float, aD[m]),
                __builtin_bit_cast(float, aSS[m]), __builtin_bit_cast(float, aDD[m]));
    }
    __syncthreads();

    // ---- stage B: vertical 11-tap via MFMA ----
    // wave = N-tile n (cols 16n..16n+15); M-tiles m=0,1 (out rows 16m..16m+15);
    // K-tiles per m: h-rows 16m..16m+15 (c=0) and 16m+16..16m+31 (c=1).
    // A[ly][k=4t+i] = gw[16c + 4t+i - ly] (ly=lane&15, t=lane>>4).
    // B[k=4t+i][x]  = h[base + 4t+i][16n + (lane&15)].
    // D col=lane&15, row=4*(lane>>4)+reg (guide m89, dtype-independent).
    const int lane = tid & 63;
    const int nT   = tid >> 6;            // N-tile = wave id
    const int t    = lane >> 4;
    const int colL = lane & 15;
    const int x    = (nT << 4) | colL;    // px col 0..63
    const int p    = x >> 1;              // pair slot
    const unsigned sel = (x & 1) ? 0x07060302u : 0x05040100u;

    // weight fragments for K-tile offset c=0,1 (built once, amortized)
    f16x4 afrag[2];
    #pragma unroll
    for (int c = 0; c < 2; ++c) {
        float av[4];
        #pragma unroll
        for (int i = 0; i < 4; ++i) {
            const int idx = 16 * c + 4 * t + i - colL;
            float v = 0.f;
            #pragma unroll
            for (int j = 0; j < 11; ++j) v = (idx == j) ? gwf[j] : v;
            av[i] = v;
        }
        uint2 au;
        au.x = pku(av[0], av[1]);
        au.y = pku(av[2], av[3]);
        afrag[c] = __builtin_bit_cast(f16x4, au);
    }

    f32x4 Dacc[2][4];   // [m][field]
    #pragma unroll
    for (int m = 0; m < 2; ++m)
        #pragma unroll
        for (int f = 0; f < 4; ++f)
            Dacc[m][f] = (f32x4){0.f, 0.f, 0.f, 0.f};

    // 3 distinct K-windows: base 0 (m0c0), 16 (m0c1 = m1c0), 32 (m1c1)
    #pragma unroll
    for (int bi = 0; bi < 3; ++bi) {
        const int base = bi << 4;
        float4 ld[4];
        #pragma unroll
        for (int i = 0; i < 4; ++i) {
            const int r = base + 4 * t + i;
            ld[i] = sAB[r][(p + r) & 31];        // un-rotate
        }
        const unsigned* w0 = (const unsigned*)&ld[0];
        const unsigned* w1 = (const unsigned*)&ld[1];
        const unsigned* w2 = (const unsigned*)&ld[2];
        const unsigned* w3 = (const unsigned*)&ld[3];

        f16x4 bf[4];
        #pragma unroll
        for (int f = 0; f < 4; ++f) {
            uint2 bu;
            bu.x = __builtin_amdgcn_perm(w1[f], w0[f], sel);   // halves k=4t+0,4t+1
            bu.y = __builtin_amdgcn_perm(w3[f], w2[f], sel);   // halves k=4t+2,4t+3
            bf[f] = __builtin_bit_cast(f16x4, bu);
        }

        if (bi == 0) {
            #pragma unroll
            for (int f = 0; f < 4; ++f)
                Dacc[0][f] = __builtin_amdgcn_mfma_f32_16x16x16f16(
                                 afrag[0], bf[f], Dacc[0][f], 0, 0, 0);
        } else if (bi == 1) {
            #pragma unroll
            for (int f = 0; f < 4; ++f) {
                Dacc[0][f] = __builtin_amdgcn_mfma_f32_16x16x16f16(
                                 afrag[1], bf[f], Dacc[0][f], 0, 0, 0);
                Dacc[1][f] = __builtin_amdgcn_mfma_f32_16x16x16f16(
                                 afrag[0], bf[f], Dacc[1][f], 0, 0, 0);
            }
        } else {
            #pragma unroll
            for (int f = 0; f < 4; ++f)
                Dacc[1][f] = __builtin_amdgcn_mfma_f32_16x16x16f16(
                                 afrag[1], bf[f], Dacc[1][f], 0, 0, 0);
        }
    }

    // ---- SSIM epilogue (fp32), S/D algebra; 8 px per thread ----
    //   2mu12+C1 = 0.5(A^2-B^2)+C1 ; mu1^2+mu2^2+C1 = 0.5(A^2+B^2)+C1
    //   2s12+C2  = 0.5((X-Y)-(A^2-B^2))+C2 ; s1+s2+C2 = 0.5((X+Y)-(A^2+B^2))+C2
    float ssim = 0.f;
    #pragma unroll
    for (int m = 0; m < 2; ++m) {
        #pragma unroll
        for (int j = 0; j < 4; ++j) {
            const float A = Dacc[m][0][j];
            const float B = Dacc[m][1][j];
            const float X = Dacc[m][2][j];
            const float Y = Dacc[m][3][j];
            const float a2 = A * A;
            const float b2 = B * B;
            const float P1 = a2 + b2;
            const float M1 = a2 - b2;
            const float num1 = fmaf(0.5f, M1, SSIM_C1);
            const float den1 = fmaf(0.5f, P1, SSIM_C1);
            const float num2 = fmaf(0.5f, (X - Y) - M1, SSIM_C2);
            const float den2 = fmaf(0.5f, (X + Y) - P1, SSIM_C2);
            ssim = fmaf(num1 * num2, __builtin_amdgcn_rcpf(den1 * den2), ssim);
        }
    }

    // ---- reduction: wave shuffle -> LDS -> 2 plain atomics into a spread slot ----
    #pragma unroll
    for (int off = 32; off > 0; off >>= 1) {
        mse  += __shfl_down(mse, off);
        ssim += __shfl_down(ssim, off);
    }
    const int wid = tid >> 6;
    if ((tid & 63) == 0) { red[0][wid] = mse; red[1][wid] = ssim; }
    __syncthreads();
    if (tid == 0) {
        const float m = red[0][0] + red[0][1] + red[0][2] + red[0][3];
        const float s = red[1][0] + red[1][1] + red[1][2] + red[1][3];
        const int bid  = (blockIdx.z * gridDim.y + blockIdx.y) * gridDim.x + blockIdx.x;
        const int slot = (bid & (NSLOT - 1)) * 16;     // 64B apart -> no line bouncing
        atomicAdd(&ws[slot + 0], m);
        atomicAdd(&ws[slot + 1], s);
    }
}

__global__ void finalize_loss(const float* __restrict__ ws,
                              float* __restrict__ out, float invN) {
    const int t = threadIdx.x;           // 64 threads
    float m = ws[t * 16 + 0];
    float s = ws[t * 16 + 1];
    #pragma unroll
    for (int off = 32; off > 0; off >>= 1) {
        m += __shfl_down(m, off);
        s += __shfl_down(s, off);
    }
    if (t == 0) out[0] = m * invN + 0.01f * (1.f - s * invN);
}

extern "C" void kernel_launch(void* const* d_in, const int* in_sizes, int n_in,
                              void* d_out, int out_size, void* d_ws, size_t ws_size,
                              hipStream_t stream) {
    const float* P = (const float*)d_in[0];
    const float* T = (const float*)d_in[1];
    float* out = (float*)d_out;
    float* ws  = (float*)d_ws;

    const int planes = in_sizes[0] / (WSZ * WSZ);     // 96
    const float invN = 1.f / (float)in_sizes[0];

    (void)hipMemsetAsync(ws, 0, NSLOT * 16 * sizeof(float), stream);
    dim3 grid(GX, GY, planes);
    fused_mse_ssim<<<grid, 256, 0, stream>>>(P, T, ws);
    finalize_loss<<<1, 64, 0, stream>>>(ws, out, invN);
}

// Round 8
// 224.657 us; speedup vs baseline: 8.6095x; 1.0307x over previous
//
#include <hip/hip_runtime.h>
#include <hip/hip_fp16.h>

// Fused MSE + SSIM loss, 32x3x512x512 fp32, MI355X — R12.
// R11 post-mortem (95.5us = R5, no gain despite MFMA working):
//  (a) A-frag cndmask build = 176 VALU/thread = 22 ops/px — cancelled the MFMA
//      savings (VALUBusy-time ROSE 68->76us).
//  (b) rotation store col (4q+m+r)&31 -> bank 16q%32 -> 4-way store conflicts;
//      SQ_LDS_BANK_CONFLICT 2.75M -> 8.55M (~15% of block time).
// R12 fixes both, keeping the verified MFMA stage B:
//  (1) afrag from __constant__ GWPAD[48] (zero-padded taps): 8 cached loads
//      + 4 pkrtz instead of 176 cndmask ops.
//  (2) bijective bank-disperse perm pi(pos) = [b1,b0,b2,b4^b1,b3^b0] used at
//      store AND read. Store (m fixed, q varies): (b2,b3,b4) bijective -> 8
//      distinct bank-quads. Read (t-group, p=8n+j): (b0,b1,b2) bijective -> 8
//      distinct bank-quads. Read col is row-independent -> computed once,
//      ds_read offsets become immediates.
// Ending: spread-slot atomics + separate finalize (R7 lesson).

#define WSZ   512
#define TW    64
#define TH    32
#define HALO  5
#define IN_H  (TH + 2*HALO)    // 42 rows of horizontal-pass output
#define BUFR  48               // padded to 48 for MFMA K-tile reads
#define GX    (WSZ / TW)       // 8
#define GY    (WSZ / TH)       // 16
#define NSLOT 64
#define SSIM_C1 0.0001f
#define SSIM_C2 0.0009f

// 11-tap gaussian, sigma=1.5, normalized
#define W0 0.00102838f
#define W1 0.00759876f
#define W2 0.03600080f
#define W3 0.10936080f
#define W4 0.21300560f
#define W5 0.26601170f

typedef _Float16 f16x4 __attribute__((ext_vector_type(4)));
typedef float    f32x4 __attribute__((ext_vector_type(4)));

// zero-padded gaussian: GWPAD[16+k] = gw[k], k=0..10
__device__ __constant__ float GWPAD[48] = {
    0,0,0,0,0,0,0,0,0,0,0,0,0,0,0,0,
    W0,W1,W2,W3,W4,W5,W4,W3,W2,W1,W0,
    0,0,0,0,0,0,0,0,0,0,0,0,0,0,0,0,0,0,0,0,0
};

static __device__ __forceinline__ __half2 pk(float a, float b) {
    return __builtin_bit_cast(__half2, __builtin_amdgcn_cvt_pkrtz(a, b));
}
static __device__ __forceinline__ unsigned pku(float a, float b) {
    return __builtin_bit_cast(unsigned, __builtin_amdgcn_cvt_pkrtz(a, b));
}
// staggered pair: (lo.hi, hi.lo) == (x[2u+1], x[2u+2])
static __device__ __forceinline__ __half2 stagger(__half2 hi, __half2 lo) {
    return __builtin_bit_cast(__half2,
        __builtin_amdgcn_alignbit(__builtin_bit_cast(unsigned, hi),
                                  __builtin_bit_cast(unsigned, lo), 16));
}
// bank-disperse permutation on 0..31: out = [b1,b0,b2,b4^b1,b3^b0]
static __device__ __forceinline__ int pi32(int pos) {
    const int b0 = pos & 1, b1 = (pos >> 1) & 1, b2 = (pos >> 2) & 1;
    const int b3 = (pos >> 3) & 1, b4 = (pos >> 4) & 1;
    return (b1 << 4) | (b0 << 3) | (b2 << 2) | ((b4 ^ b1) << 1) | (b3 ^ b0);
}

__launch_bounds__(256, 6)
__global__ void fused_mse_ssim(const float* __restrict__ P,
                               const float* __restrict__ T,
                               float* __restrict__ ws) {
    __shared__ float4 sAB[BUFR][32];    // fields per slot: S, D, SS, DD (half2)
    __shared__ float  red[2][4];

    const int tid = threadIdx.x;
    const int gx0 = blockIdx.x * TW;
    const int gy0 = blockIdx.y * TH;
    const size_t plane = (size_t)blockIdx.z * (WSZ * (size_t)WSZ);
    const float* Pp = P + plane;
    const float* Tp = T + plane;
    const bool xedge = (blockIdx.x == 0) || (blockIdx.x == GX - 1);

    const float gwf[11] = {W0,W1,W2,W3,W4,W5,W4,W3,W2,W1,W0};
    unsigned gwh[11];   // half2(w,w) bit patterns, wave-uniform -> SGPR
    #pragma unroll
    for (int k = 0; k < 11; ++k)
        gwh[k] = __builtin_amdgcn_readfirstlane(
                     __builtin_bit_cast(unsigned, __float2half2_rn(gwf[k])));

    float mse = 0.f;

    // zero-fill pad rows 42..47 (MFMA K-tiles read up to row 47)
    if (tid < 192)
        sAB[IN_H + (tid >> 5)][tid & 31] = make_float4(0.f, 0.f, 0.f, 0.f);

    // ---- stage A (R5-proven): packed-fp16 horizontal 11-tap on S,D,S^2,D^2 ----
    for (int it = tid; it < IN_H * 8; it += 256) {
        const int r  = it >> 3;
        const int q  = it & 7;
        const int gy = gy0 - HALO + r;
        const int cb = gx0 + q * 8 - 8;            // leftmost loaded px (16B aligned)
        const float* prow = Pp + ((long)gy * WSZ + cb);
        const float* trow = Tp + ((long)gy * WSZ + cb);
        const bool rv   = ((unsigned)gy < (unsigned)WSZ);
        const bool mrow = ((unsigned)(r - HALO) < (unsigned)TH);

        const __half2 z = __float2half2_rn(0.f);
        __half2 As[12], Ad[12];

        if (!xedge) {
            if (rv) {
                #pragma unroll
                for (int b = 0; b < 6; ++b) {
                    const float4 pv = *(const float4*)(prow + 4 * b);
                    const float4 tv = *(const float4*)(trow + 4 * b);
                    const float s0 = pv.x + tv.x, s1 = pv.y + tv.y;
                    const float s2 = pv.z + tv.z, s3 = pv.w + tv.w;
                    const float d0 = pv.x - tv.x, d1 = pv.y - tv.y;
                    const float d2 = pv.z - tv.z, d3 = pv.w - tv.w;
                    As[2*b]   = pk(s0, s1); As[2*b+1] = pk(s2, s3);
                    Ad[2*b]   = pk(d0, d1); Ad[2*b+1] = pk(d2, d3);
                    if ((b == 2 || b == 3) && mrow) {
                        mse = fmaf(d0, d0, mse); mse = fmaf(d1, d1, mse);
                        mse = fmaf(d2, d2, mse); mse = fmaf(d3, d3, mse);
                    }
                }
            } else {
                #pragma unroll
                for (int b = 0; b < 12; ++b) { As[b] = z; Ad[b] = z; }
            }
        } else {
            #pragma unroll
            for (int b = 0; b < 6; ++b) {
                const unsigned cc = (unsigned)(cb + 4 * b);
                float4 pv = make_float4(0.f, 0.f, 0.f, 0.f);
                float4 tv = make_float4(0.f, 0.f, 0.f, 0.f);
                if (rv && cc < (unsigned)WSZ) {
                    pv = *(const float4*)(prow + 4 * b);
                    tv = *(const float4*)(trow + 4 * b);
                }
                const float s0 = pv.x + tv.x, s1 = pv.y + tv.y;
                const float s2 = pv.z + tv.z, s3 = pv.w + tv.w;
                const float d0 = pv.x - tv.x, d1 = pv.y - tv.y;
                const float d2 = pv.z - tv.z, d3 = pv.w - tv.w;
                As[2*b]   = pk(s0, s1); As[2*b+1] = pk(s2, s3);
                Ad[2*b]   = pk(d0, d1); Ad[2*b+1] = pk(d2, d3);
                if ((b == 2 || b == 3) && mrow) {
                    mse = fmaf(d0, d0, mse); mse = fmaf(d1, d1, mse);
                    mse = fmaf(d2, d2, mse); mse = fmaf(d3, d3, mse);
                }
            }
        }

        // packed conv: output pair m (=out px 2m,2m+1) needs px[3+2m+k], k=0..10
        __half2 aS[4]  = {z, z, z, z};
        __half2 aD[4]  = {z, z, z, z};
        __half2 aSS[4] = {z, z, z, z};
        __half2 aDD[4] = {z, z, z, z};

        #pragma unroll
        for (int jj = 0; jj <= 16; ++jj) {
            const int j = jj + 3;
            __half2 vs, vd;
            if (j & 1) {
                vs = stagger(As[(j >> 1) + 1], As[j >> 1]);
                vd = stagger(Ad[(j >> 1) + 1], Ad[j >> 1]);
            } else {
                vs = As[j >> 1];
                vd = Ad[j >> 1];
            }
            const __half2 vss = __hmul2(vs, vs);
            const __half2 vdd = __hmul2(vd, vd);
            #pragma unroll
            for (int m = 0; m < 4; ++m) {
                const int k = jj - 2 * m;
                if (k >= 0 && k < 11) {
                    const __half2 w = __builtin_bit_cast(__half2, gwh[k]);
                    aS[m]  = __hfma2(w, vs,  aS[m]);
                    aD[m]  = __hfma2(w, vd,  aD[m]);
                    aSS[m] = __hfma2(w, vss, aSS[m]);
                    aDD[m] = __hfma2(w, vdd, aDD[m]);
                }
            }
        }

        // bank-disperse store: pair pos = 4q+m lives at col pi32(pos)
        #pragma unroll
        for (int m = 0; m < 4; ++m)
            sAB[r][pi32(4 * q + m)] = make_float4(
                __builtin_bit_cast(float, aS[m]),  __builtin_bit_cast(float, aD[m]),
                __builtin_bit_cast(float, aSS[m]), __builtin_bit_cast(float, aDD[m]));
    }
    __syncthreads();

    // ---- stage B: vertical 11-tap via MFMA (R11-verified mapping) ----
    // wave = N-tile n (cols 16n..16n+15); M-tiles m=0,1 (out rows 16m..16m+15);
    // A[ly][k=4t+i] = gw[16c + 4t+i - ly] (ly=lane&15, t=lane>>4).
    // B[k=4t+i][x]  = h[base + 4t+i][16n + (lane&15)].
    const int lane = tid & 63;
    const int nT   = tid >> 6;            // N-tile = wave id
    const int t    = lane >> 4;
    const int colL = lane & 15;
    const int x    = (nT << 4) | colL;    // px col 0..63
    const int p    = x >> 1;              // pair index
    const int colR = pi32(p);             // LDS col (row-independent!)
    const unsigned sel = (x & 1) ? 0x07060302u : 0x05040100u;

    // weight fragments for K-tile offset c=0,1: 8 constant-table loads + 4 pkrtz
    f16x4 afrag[2];
    #pragma unroll
    for (int c = 0; c < 2; ++c) {
        float av[4];
        #pragma unroll
        for (int i = 0; i < 4; ++i)
            av[i] = GWPAD[16 * c + 4 * t + i - colL + 16];
        uint2 au;
        au.x = pku(av[0], av[1]);
        au.y = pku(av[2], av[3]);
        afrag[c] = __builtin_bit_cast(f16x4, au);
    }

    f32x4 Dacc[2][4];   // [m][field]
    #pragma unroll
    for (int m = 0; m < 2; ++m)
        #pragma unroll
        for (int f = 0; f < 4; ++f)
            Dacc[m][f] = (f32x4){0.f, 0.f, 0.f, 0.f};

    // 3 distinct K-windows: base 0 (m0c0), 16 (m0c1 = m1c0), 32 (m1c1)
    #pragma unroll
    for (int bi = 0; bi < 3; ++bi) {
        const int base = bi << 4;
        float4 ld[4];
        #pragma unroll
        for (int i = 0; i < 4; ++i)
            ld[i] = sAB[base + 4 * t + i][colR];
        const unsigned* w0 = (const unsigned*)&ld[0];
        const unsigned* w1 = (const unsigned*)&ld[1];
        const unsigned* w2 = (const unsigned*)&ld[2];
        const unsigned* w3 = (const unsigned*)&ld[3];

        f16x4 bf[4];
        #pragma unroll
        for (int f = 0; f < 4; ++f) {
            uint2 bu;
            bu.x = __builtin_amdgcn_perm(w1[f], w0[f], sel);   // halves k=4t+0,4t+1
            bu.y = __builtin_amdgcn_perm(w3[f], w2[f], sel);   // halves k=4t+2,4t+3
            bf[f] = __builtin_bit_cast(f16x4, bu);
        }

        if (bi == 0) {
            #pragma unroll
            for (int f = 0; f < 4; ++f)
                Dacc[0][f] = __builtin_amdgcn_mfma_f32_16x16x16f16(
                                 afrag[0], bf[f], Dacc[0][f], 0, 0, 0);
        } else if (bi == 1) {
            #pragma unroll
            for (int f = 0; f < 4; ++f) {
                Dacc[0][f] = __builtin_amdgcn_mfma_f32_16x16x16f16(
                                 afrag[1], bf[f], Dacc[0][f], 0, 0, 0);
                Dacc[1][f] = __builtin_amdgcn_mfma_f32_16x16x16f16(
                                 afrag[0], bf[f], Dacc[1][f], 0, 0, 0);
            }
        } else {
            #pragma unroll
            for (int f = 0; f < 4; ++f)
                Dacc[1][f] = __builtin_amdgcn_mfma_f32_16x16x16f16(
                                 afrag[1], bf[f], Dacc[1][f], 0, 0, 0);
        }
    }

    // ---- SSIM epilogue (fp32), S/D algebra; 8 px per thread ----
    //   2mu12+C1 = 0.5(A^2-B^2)+C1 ; mu1^2+mu2^2+C1 = 0.5(A^2+B^2)+C1
    //   2s12+C2  = 0.5((X-Y)-(A^2-B^2))+C2 ; s1+s2+C2 = 0.5((X+Y)-(A^2+B^2))+C2
    float ssim = 0.f;
    #pragma unroll
    for (int m = 0; m < 2; ++m) {
        #pragma unroll
        for (int j = 0; j < 4; ++j) {
            const float A = Dacc[m][0][j];
            const float B = Dacc[m][1][j];
            const float X = Dacc[m][2][j];
            const float Y = Dacc[m][3][j];
            const float a2 = A * A;
            const float b2 = B * B;
            const float P1 = a2 + b2;
            const float M1 = a2 - b2;
            const float num1 = fmaf(0.5f, M1, SSIM_C1);
            const float den1 = fmaf(0.5f, P1, SSIM_C1);
            const float num2 = fmaf(0.5f, (X - Y) - M1, SSIM_C2);
            const float den2 = fmaf(0.5f, (X + Y) - P1, SSIM_C2);
            ssim = fmaf(num1 * num2, __builtin_amdgcn_rcpf(den1 * den2), ssim);
        }
    }

    // ---- reduction: wave shuffle -> LDS -> 2 plain atomics into a spread slot ----
    #pragma unroll
    for (int off = 32; off > 0; off >>= 1) {
        mse  += __shfl_down(mse, off);
        ssim += __shfl_down(ssim, off);
    }
    const int wid = tid >> 6;
    if ((tid & 63) == 0) { red[0][wid] = mse; red[1][wid] = ssim; }
    __syncthreads();
    if (tid == 0) {
        const float m = red[0][0] + red[0][1] + red[0][2] + red[0][3];
        const float s = red[1][0] + red[1][1] + red[1][2] + red[1][3];
        const int bid  = (blockIdx.z * gridDim.y + blockIdx.y) * gridDim.x + blockIdx.x;
        const int slot = (bid & (NSLOT - 1)) * 16;     // 64B apart -> no line bouncing
        atomicAdd(&ws[slot + 0], m);
        atomicAdd(&ws[slot + 1], s);
    }
}

__global__ void finalize_loss(const float* __restrict__ ws,
                              float* __restrict__ out, float invN) {
    const int t = threadIdx.x;           // 64 threads
    float m = ws[t * 16 + 0];
    float s = ws[t * 16 + 1];
    #pragma unroll
    for (int off = 32; off > 0; off >>= 1) {
        m += __shfl_down(m, off);
        s += __shfl_down(s, off);
    }
    if (t == 0) out[0] = m * invN + 0.01f * (1.f - s * invN);
}

extern "C" void kernel_launch(void* const* d_in, const int* in_sizes, int n_in,
                              void* d_out, int out_size, void* d_ws, size_t ws_size,
                              hipStream_t stream) {
    const float* P = (const float*)d_in[0];
    const float* T = (const float*)d_in[1];
    float* out = (float*)d_out;
    float* ws  = (float*)d_ws;

    const int planes = in_sizes[0] / (WSZ * WSZ);     // 96
    const float invN = 1.f / (float)in_sizes[0];

    (void)hipMemsetAsync(ws, 0, NSLOT * 16 * sizeof(float), stream);
    dim3 grid(GX, GY, planes);
    fused_mse_ssim<<<grid, 256, 0, stream>>>(P, T, ws);
    finalize_loss<<<1, 64, 0, stream>>>(ws, out, invN);
}